// Round 4
// baseline (1449.632 us; speedup 1.0000x reference)
//
#include <hip/hip_runtime.h>
#include <cstdint>
#include <cstddef>

#define EPS 1e-5f

typedef __attribute__((ext_vector_type(8))) short bf16x8;
typedef __attribute__((ext_vector_type(4))) float f32x4;

__device__ __forceinline__ unsigned short rne_bf16(float f) {
  union { float f; unsigned int u; } v; v.f = f;
  unsigned int u = v.u;
  return (unsigned short)((u + 0x7fffu + ((u >> 16) & 1u)) >> 16);
}
__device__ __forceinline__ float bf16_to_f(unsigned short h) {
  union { unsigned int u; float f; } v; v.u = ((unsigned int)h) << 16; return v.f;
}
// split fp32 into hi/lo bf16 pair: hi+lo represents v to ~2^-17 relative
__device__ __forceinline__ void split_hl(float v, unsigned short& h, unsigned short& l) {
  h = rne_bf16(v);
  l = rne_bf16(v - bf16_to_f(h));
}
__device__ __forceinline__ f32x4 mfma16(bf16x8 a, bf16x8 b, f32x4 c) {
  return __builtin_amdgcn_mfma_f32_16x16x32_bf16(a, b, c, 0, 0, 0);
}

// ---------------------------------------------------------------------------
// Stage 1: fc1. h_t[b][k][m] = x[b]·fc1_w[m*128+k] + fc1_b.  One wave per row.
// ---------------------------------------------------------------------------
__global__ __launch_bounds__(256) void k_fc1(const float* __restrict__ x,
                                             const float* __restrict__ w,
                                             const float* __restrict__ bias,
                                             float* __restrict__ h_t) {
  const int lane = threadIdx.x & 63;
  const int wv = threadIdx.x >> 6;
  const int r = blockIdx.x * 4 + wv;               // weight row 0..32767
  const float4* wr = (const float4*)(w + (size_t)r * 1024);
  float acc[8] = {0, 0, 0, 0, 0, 0, 0, 0};
#pragma unroll
  for (int i = 0; i < 4; ++i) {
    float4 wv4 = wr[lane + i * 64];
#pragma unroll
    for (int b = 0; b < 8; ++b) {
      float4 xv = ((const float4*)(x + b * 1024))[lane + i * 64];
      acc[b] += wv4.x * xv.x + wv4.y * xv.y + wv4.z * xv.z + wv4.w * xv.w;
    }
  }
#pragma unroll
  for (int d = 1; d < 64; d <<= 1) {
#pragma unroll
    for (int b = 0; b < 8; ++b) acc[b] += __shfl_xor(acc[b], d);
  }
  if (lane == 0) {
    const int mm = r >> 7, kk = r & 127;
    const float bb = bias[r];
#pragma unroll
    for (int b = 0; b < 8; ++b) h_t[b * 32768 + kk * 256 + mm] = acc[b] + bb;
  }
}

// ---------------------------------------------------------------------------
// Stage 2a: conv1 + BN + ReLU (fp32).
// ---------------------------------------------------------------------------
__global__ __launch_bounds__(256) void k_conv1(
    const float* __restrict__ h_t,
    const float* __restrict__ c1q_w, const float* __restrict__ c1q_b,
    const float* __restrict__ c1v_w, const float* __restrict__ c1v_b,
    const float* __restrict__ g1q, const float* __restrict__ be1q,
    const float* __restrict__ mu1q, const float* __restrict__ va1q,
    const float* __restrict__ g1k, const float* __restrict__ be1k,
    const float* __restrict__ mu1k, const float* __restrict__ va1k,
    const float* __restrict__ g1v, const float* __restrict__ be1v,
    const float* __restrict__ mu1v, const float* __restrict__ va1v,
    float* __restrict__ T1q, float* __restrict__ T1k, float* __restrict__ T1v) {
  const int m = threadIdx.x;
  const int o = blockIdx.x & 63;
  const int b = blockIdx.x >> 6;
  const int path = blockIdx.y;
  const float* w = (path == 0 ? c1q_w : c1v_w) + o * 128;
  const float* h = h_t + b * 32768 + m;
  float acc = 0.f;
#pragma unroll 8
  for (int c = 0; c < 128; ++c) acc += w[c] * h[c * 256];
  if (path == 0) {
    const float z = acc + c1q_b[o];
    const float sq = g1q[o] / sqrtf(va1q[o] + EPS);
    T1q[b * 16384 + o * 256 + m] = fmaxf((z - mu1q[o]) * sq + be1q[o], 0.f);
    const float sk = g1k[o] / sqrtf(va1k[o] + EPS);
    T1k[b * 16384 + o * 256 + m] = fmaxf((z - mu1k[o]) * sk + be1k[o], 0.f);
  } else {
    const float z = acc + c1v_b[o];
    const float sv = g1v[o] / sqrtf(va1v[o] + EPS);
    T1v[b * 16384 + o * 256 + m] = fmaxf((z - mu1v[o]) * sv + be1v[o], 0.f);
  }
}

// ---------------------------------------------------------------------------
// Stage 2b: conv2 + BN + ReLU, output TRANSPOSED hi/lo bf16 [b][m(256)][c2(128)]
// ---------------------------------------------------------------------------
__global__ __launch_bounds__(256) void k_conv2(
    const float* __restrict__ T1q, const float* __restrict__ T1k,
    const float* __restrict__ T1v,
    const float* __restrict__ c2q_w, const float* __restrict__ c2q_b,
    const float* __restrict__ c2v_w, const float* __restrict__ c2v_b,
    const float* __restrict__ g2q, const float* __restrict__ be2q,
    const float* __restrict__ mu2q, const float* __restrict__ va2q,
    const float* __restrict__ g2k, const float* __restrict__ be2k,
    const float* __restrict__ mu2k, const float* __restrict__ va2k,
    const float* __restrict__ g2v, const float* __restrict__ be2v,
    const float* __restrict__ mu2v, const float* __restrict__ va2v,
    unsigned short* __restrict__ Q2H, unsigned short* __restrict__ Q2L,
    unsigned short* __restrict__ K2H, unsigned short* __restrict__ K2L,
    unsigned short* __restrict__ V2H, unsigned short* __restrict__ V2L) {
  const int m = threadIdx.x;
  const int b = blockIdx.x;
  const int path = blockIdx.y;
  const int oc = blockIdx.z;
  const float* T1 = (path == 0 ? T1q : path == 1 ? T1k : T1v) + b * 16384 + m;
  const float* w = (path == 2 ? c2v_w : c2q_w);
  const float* cb = (path == 2 ? c2v_b : c2q_b);
  const float* g = (path == 0 ? g2q : path == 1 ? g2k : g2v);
  const float* be = (path == 0 ? be2q : path == 1 ? be2k : be2v);
  const float* mu = (path == 0 ? mu2q : path == 1 ? mu2k : mu2v);
  const float* va = (path == 0 ? va2q : path == 1 ? va2k : va2v);
  float t[64];
#pragma unroll 8
  for (int c = 0; c < 64; ++c) t[c] = T1[c * 256];
  unsigned short* oh =
      (path == 0 ? Q2H : path == 1 ? K2H : V2H) + b * 32768 + m * 128 + oc * 64;
  unsigned short* ol =
      (path == 0 ? Q2L : path == 1 ? K2L : V2L) + b * 32768 + m * 128 + oc * 64;
  for (int og = 0; og < 8; ++og) {
    bf16x8 ph, pl;
#pragma unroll
    for (int j = 0; j < 8; ++j) {
      const int o = oc * 64 + og * 8 + j;
      float acc = cb[o];
      const float* wo = w + o * 64;
#pragma unroll 8
      for (int c = 0; c < 64; ++c) acc += wo[c] * t[c];
      const float s = g[o] / sqrtf(va[o] + EPS);
      const float val = fmaxf((acc - mu[o]) * s + be[o], 0.f);
      unsigned short hh, ll;
      split_hl(val, hh, ll);
      ph[j] = (short)hh; pl[j] = (short)ll;
    }
    *(bf16x8*)(oh + og * 8) = ph;
    *(bf16x8*)(ol + og * 8) = pl;
  }
}

// ---------------------------------------------------------------------------
// Stage 3a: conv3 for Q or K via split-MFMA (~fp32), output hi/lo bf16 pair
// Y[b][n][m].  Q scaled by 1/sqrt(128).
// ---------------------------------------------------------------------------
__global__ __launch_bounds__(256) void k_conv3qk(
    const float* __restrict__ W, const float* __restrict__ bias,
    const unsigned short* __restrict__ Xh, const unsigned short* __restrict__ Xl,
    unsigned short* __restrict__ Yh, unsigned short* __restrict__ Yl,
    float scale) {
  const int lane = threadIdx.x & 63, wv = threadIdx.x >> 6;
  const int l15 = lane & 15, quad = lane >> 4;
  const int b = blockIdx.y;
  const unsigned short* XH = Xh + b * 32768;
  const unsigned short* XL = Xl + b * 32768;
  unsigned short* YH = Yh + (size_t)b * 4096 * 256;
  unsigned short* YL = Yl + (size_t)b * 4096 * 256;
  const int nb = blockIdx.x * 64 + wv * 16;
  const float* wr = W + (size_t)(nb + l15) * 128 + quad * 8;
  bf16x8 ah[4], al[4];
#pragma unroll
  for (int ks = 0; ks < 4; ++ks) {
#pragma unroll
    for (int j = 0; j < 8; ++j) {
      unsigned short hh, ll;
      split_hl(wr[ks * 32 + j], hh, ll);
      ah[ks][j] = (short)hh; al[ks][j] = (short)ll;
    }
  }
  f32x4 acc[16];
#pragma unroll
  for (int ms = 0; ms < 16; ++ms) acc[ms] = (f32x4){0, 0, 0, 0};
#pragma unroll
  for (int ks = 0; ks < 4; ++ks) {
#pragma unroll
    for (int ms = 0; ms < 16; ++ms) {
      const size_t off = (size_t)(ms * 16 + l15) * 128 + ks * 32 + quad * 8;
      bf16x8 bh = *(const bf16x8*)(XH + off);
      bf16x8 bl = *(const bf16x8*)(XL + off);
      acc[ms] = mfma16(ah[ks], bh, acc[ms]);
      acc[ms] = mfma16(al[ks], bh, acc[ms]);
      acc[ms] = mfma16(ah[ks], bl, acc[ms]);
    }
  }
#pragma unroll
  for (int r = 0; r < 4; ++r) {
    const int n = nb + quad * 4 + r;
    const float bv = bias[n];
#pragma unroll
    for (int ms = 0; ms < 16; ++ms) {
      const float v = (acc[ms][r] + bv) * scale;
      unsigned short hh, ll;
      split_hl(v, hh, ll);
      YH[(size_t)n * 256 + ms * 16 + l15] = hh;
      YL[(size_t)n * 256 + ms * 16 + l15] = ll;
    }
  }
}

// ---------------------------------------------------------------------------
// Stage 3b: conv3 for V (split-MFMA), output PRE-TRANSPOSED hi/lo bf16
// VhT/VlT [b][m(256)][n(4096)].
// ---------------------------------------------------------------------------
__global__ __launch_bounds__(256) void k_conv3v(
    const float* __restrict__ c3v_w, const float* __restrict__ c3v_b,
    const unsigned short* __restrict__ V2H, const unsigned short* __restrict__ V2L,
    unsigned short* __restrict__ VhT, unsigned short* __restrict__ VlT) {
  const int lane = threadIdx.x & 63, wv = threadIdx.x >> 6;
  const int l15 = lane & 15, quad = lane >> 4;
  const int b = blockIdx.z;
  const int nb0 = blockIdx.x * 256;
  const int mb = blockIdx.y * 64 + wv * 16;
  const size_t xoff = b * 32768 + (size_t)(mb + l15) * 128 + quad * 8;
  bf16x8 ah[4], al[4];
#pragma unroll
  for (int ks = 0; ks < 4; ++ks) {
    ah[ks] = *(const bf16x8*)(V2H + xoff + ks * 32);
    al[ks] = *(const bf16x8*)(V2L + xoff + ks * 32);
  }
  f32x4 acc[16];
#pragma unroll
  for (int ns = 0; ns < 16; ++ns) acc[ns] = (f32x4){0, 0, 0, 0};
#pragma unroll
  for (int ks = 0; ks < 4; ++ks) {
#pragma unroll
    for (int ns = 0; ns < 16; ++ns) {
      const float* wr = c3v_w + (size_t)(nb0 + ns * 16 + l15) * 128 + ks * 32 + quad * 8;
      bf16x8 bh, bl;
#pragma unroll
      for (int j = 0; j < 8; ++j) {
        unsigned short hh, ll;
        split_hl(wr[j], hh, ll);
        bh[j] = (short)hh; bl[j] = (short)ll;
      }
      acc[ns] = mfma16(ah[ks], bh, acc[ns]);
      acc[ns] = mfma16(al[ks], bh, acc[ns]);
      acc[ns] = mfma16(ah[ks], bl, acc[ns]);
    }
  }
#pragma unroll
  for (int ns = 0; ns < 16; ++ns) {
    const int n = nb0 + ns * 16 + l15;
    const float bv = c3v_b[n];
#pragma unroll
    for (int r = 0; r < 4; ++r) {
      const int m = mb + quad * 4 + r;
      unsigned short hh, ll;
      split_hl(acc[ns][r] + bv, hh, ll);
      VhT[(size_t)b * 1048576 + (size_t)m * 4096 + n] = hh;
      VlT[(size_t)b * 1048576 + (size_t)m * 4096 + n] = ll;
    }
  }
}

// ---------------------------------------------------------------------------
// Stage 4: flash attention, full hi/lo precision (peaked-softmax safe).
//   S = QK^T via 3 split chains (QhKh + QlKh + QhKl), ~fp32.
//   P = exp(S) stored hi/lo; l = sum of the SAME (Ph+Pl) weights.
//   PV via 2 MFMAs per m-tile: [Ph|Pl]x[Vh|Vh]  +  [Ph|Pl]x[Vl|0].
//   V stored hi/lo (VhT/VlT).  Fused co_w epilogue.
// ---------------------------------------------------------------------------
__global__ __launch_bounds__(256) void k_attn(
    const unsigned short* __restrict__ Qh, const unsigned short* __restrict__ Ql,
    const unsigned short* __restrict__ Kh, const unsigned short* __restrict__ Kl,
    const unsigned short* __restrict__ VhT, const unsigned short* __restrict__ VlT,
    const float* __restrict__ co_w, const float* __restrict__ co_b,
    float* __restrict__ out) {
  __shared__ __align__(16) short Kth[16 * 264];   // K hi tile [16][256] pad 264
  __shared__ __align__(16) short Ktl[16 * 264];   // K lo tile
  __shared__ __align__(16) short VTth[256 * 40];  // [m][k=32]: cols 0-15 Vh, 16-31 Vh dup
  __shared__ __align__(16) short VTtl[256 * 40];  // cols 0-15 Vl, 16-31 ZERO
  __shared__ __align__(16) short Pb[4 * 16 * 40]; // per-wave P: cols 0-15 Ph, 16-31 Pl
  const int t = threadIdx.x;
  const int lane = t & 63, wv = t >> 6;
  const int l15 = lane & 15, quad = lane >> 4;
  const int b = blockIdx.x & 7;     // batch ~pinned per-XCD for K/V L2 locality
  const int qt = blockIdx.x >> 3;
  for (int i = t; i < 256 * 40; i += 256) VTtl[i] = 0;   // zero (cols 16.. stay 0)
  const size_t qoff = ((size_t)b * 4096 + qt * 64 + wv * 16 + l15) * 256 + quad * 8;
  bf16x8 qh[8], ql[8];
#pragma unroll
  for (int ks = 0; ks < 8; ++ks) {
    qh[ks] = *(const bf16x8*)(Qh + qoff + ks * 32);
    ql[ks] = *(const bf16x8*)(Ql + qoff + ks * 32);
  }
  f32x4 O[16];
#pragma unroll
  for (int ms = 0; ms < 16; ++ms) O[ms] = (f32x4){0, 0, 0, 0};
  float lpart[4] = {0, 0, 0, 0};
  const unsigned short* Kgh = Kh + (size_t)b * 4096 * 256;
  const unsigned short* Kgl = Kl + (size_t)b * 4096 * 256;
  const unsigned short* Vgh = VhT + (size_t)b * 1048576;
  const unsigned short* Vgl = VlT + (size_t)b * 1048576;
  short* Pw = Pb + wv * 640;
  __syncthreads();  // zero-init visible before first staging

  for (int jt = 0; jt < 256; ++jt) {
    const int jbase = jt * 16;
#pragma unroll
    for (int c = 0; c < 2; ++c) {  // stage K hi/lo tiles [16][256]
      const int ch = c * 256 + t;
      const int row = ch >> 5, off = (ch & 31) * 8;
      const size_t g = (size_t)(jbase + row) * 256 + off;
      *(bf16x8*)&Kth[row * 264 + off] = *(const bf16x8*)(Kgh + g);
      *(bf16x8*)&Ktl[row * 264 + off] = *(const bf16x8*)(Kgl + g);
    }
#pragma unroll
    for (int c = 0; c < 2; ++c) {  // stage V^T hi/lo tiles [256][16]
      const int ch = c * 256 + t;
      const int mr = ch >> 1, off = (ch & 1) * 8;
      const size_t g = (size_t)mr * 4096 + jbase + off;
      bf16x8 vh = *(const bf16x8*)(Vgh + g);
      *(bf16x8*)&VTth[mr * 40 + off] = vh;
      *(bf16x8*)&VTth[mr * 40 + 16 + off] = vh;  // duplicate for PlVh slot
      *(bf16x8*)&VTtl[mr * 40 + off] = *(const bf16x8*)(Vgl + g);
    }
    __syncthreads();
    f32x4 s0 = {0, 0, 0, 0};
#pragma unroll
    for (int ks = 0; ks < 8; ++ks) {  // S = QK^T, split (scale folded into Q)
      bf16x8 k0h = *(const bf16x8*)&Kth[l15 * 264 + ks * 32 + quad * 8];
      bf16x8 k0l = *(const bf16x8*)&Ktl[l15 * 264 + ks * 32 + quad * 8];
      s0 = mfma16(qh[ks], k0h, s0);
      s0 = mfma16(ql[ks], k0h, s0);
      s0 = mfma16(qh[ks], k0l, s0);
    }
#pragma unroll
    for (int r = 0; r < 4; ++r) {  // P = exp(S) hi/lo; C/D -> A layout via LDS
      const float p = expf(s0[r]);
      unsigned short ph, pl;
      split_hl(p, ph, pl);
      lpart[r] += bf16_to_f(ph) + bf16_to_f(pl);  // l == weights actually used
      Pw[(quad * 4 + r) * 40 + l15] = (short)ph;
      Pw[(quad * 4 + r) * 40 + 16 + l15] = (short)pl;
    }
    __syncthreads();  // P visible
    bf16x8 pf = *(const bf16x8*)&Pw[l15 * 40 + quad * 8];  // [Ph|Pl] A-frag
#pragma unroll
    for (int ms = 0; ms < 16; ++ms) {  // O += (Ph+Pl)Vh + PhVl
      bf16x8 vfh = *(const bf16x8*)&VTth[(ms * 16 + l15) * 40 + quad * 8];
      bf16x8 vfl = *(const bf16x8*)&VTtl[(ms * 16 + l15) * 40 + quad * 8];
      O[ms] = mfma16(pf, vfh, O[ms]);
      O[ms] = mfma16(pf, vfl, O[ms]);
    }
    __syncthreads();  // protect tiles before next staging
  }
  // reduce l across the 16 lanes of each quad
#pragma unroll
  for (int r = 0; r < 4; ++r) {
#pragma unroll
    for (int d = 1; d < 16; d <<= 1) lpart[r] += __shfl_xor(lpart[r], d);
  }
  // stage co_w into (now free) K-tile LDS space
  __syncthreads();
  float* cw = (float*)Kth;
  for (int i = t; i < 768; i += 256) cw[i] = co_w[i];
  __syncthreads();
  // fused epilogue: out[b][row][o] = co_w[o]·O_row/l + co_b[o]
  float part[4][3];
#pragma unroll
  for (int r = 0; r < 4; ++r)
#pragma unroll
    for (int o = 0; o < 3; ++o) part[r][o] = 0.f;
#pragma unroll
  for (int ms = 0; ms < 16; ++ms) {
    const int m = ms * 16 + l15;
    const float c0 = cw[m], c1 = cw[256 + m], c2 = cw[512 + m];
#pragma unroll
    for (int r = 0; r < 4; ++r) {
      const float ov = O[ms][r];
      part[r][0] += ov * c0;
      part[r][1] += ov * c1;
      part[r][2] += ov * c2;
    }
  }
#pragma unroll
  for (int r = 0; r < 4; ++r) {
    const float rl = 1.f / lpart[r];
#pragma unroll
    for (int o = 0; o < 3; ++o) {
      float v = part[r][o] * rl;
#pragma unroll
      for (int d = 1; d < 16; d <<= 1) v += __shfl_xor(v, d);
      part[r][o] = v;
    }
  }
  if (l15 == 0) {
    const int rowbase = qt * 64 + wv * 16 + quad * 4;
#pragma unroll
    for (int r = 0; r < 4; ++r)
#pragma unroll
      for (int o = 0; o < 3; ++o)
        out[(size_t)b * 12288 + (size_t)(rowbase + r) * 3 + o] = part[r][o] + co_b[o];
  }
}

// ---------------------------------------------------------------------------
extern "C" void kernel_launch(void* const* d_in, const int* in_sizes, int n_in,
                              void* d_out, int out_size, void* d_ws, size_t ws_size,
                              hipStream_t stream) {
  const float* x = (const float*)d_in[0];
  const float* fc1_w = (const float*)d_in[1];
  const float* fc1_b = (const float*)d_in[2];
  const float* c1q_w = (const float*)d_in[3];
  const float* c1q_b = (const float*)d_in[4];
  const float* c2q_w = (const float*)d_in[5];
  const float* c2q_b = (const float*)d_in[6];
  const float* c3q_w = (const float*)d_in[7];
  const float* c3q_b = (const float*)d_in[8];
  const float* c3k_w = (const float*)d_in[9];
  const float* c3k_b = (const float*)d_in[10];
  const float* c1v_w = (const float*)d_in[11];
  const float* c1v_b = (const float*)d_in[12];
  const float* c2v_w = (const float*)d_in[13];
  const float* c2v_b = (const float*)d_in[14];
  const float* c3v_w = (const float*)d_in[15];
  const float* c3v_b = (const float*)d_in[16];
  const float* bn1q_g = (const float*)d_in[17];
  const float* bn1q_be = (const float*)d_in[18];
  const float* bn1q_m = (const float*)d_in[19];
  const float* bn1q_v = (const float*)d_in[20];
  const float* bn2q_g = (const float*)d_in[21];
  const float* bn2q_be = (const float*)d_in[22];
  const float* bn2q_m = (const float*)d_in[23];
  const float* bn2q_v = (const float*)d_in[24];
  const float* bn1k_g = (const float*)d_in[25];
  const float* bn1k_be = (const float*)d_in[26];
  const float* bn1k_m = (const float*)d_in[27];
  const float* bn1k_v = (const float*)d_in[28];
  const float* bn2k_g = (const float*)d_in[29];
  const float* bn2k_be = (const float*)d_in[30];
  const float* bn2k_m = (const float*)d_in[31];
  const float* bn2k_v = (const float*)d_in[32];
  const float* bn1v_g = (const float*)d_in[33];
  const float* bn1v_be = (const float*)d_in[34];
  const float* bn1v_m = (const float*)d_in[35];
  const float* bn1v_v = (const float*)d_in[36];
  const float* bn2v_g = (const float*)d_in[37];
  const float* bn2v_be = (const float*)d_in[38];
  const float* bn2v_m = (const float*)d_in[39];
  const float* bn2v_v = (const float*)d_in[40];
  const float* co_w = (const float*)d_in[41];
  const float* co_b = (const float*)d_in[42];

  char* ws = (char*)d_ws;
  float* h_t = (float*)(ws + 0);                            // 1 MB [8][128][256]
  float* T1q = (float*)(ws + 1048576);                      // 512KB each
  float* T1k = (float*)(ws + 1572864);
  float* T1v = (float*)(ws + 2097152);
  unsigned short* Q2H = (unsigned short*)(ws + 2621440);    // 512KB each, [8][256][128]
  unsigned short* Q2L = (unsigned short*)(ws + 3145728);
  unsigned short* K2H = (unsigned short*)(ws + 3670016);
  unsigned short* K2L = (unsigned short*)(ws + 4194304);
  unsigned short* V2H = (unsigned short*)(ws + 4718592);
  unsigned short* V2L = (unsigned short*)(ws + 5242880);
  unsigned short* QhB = (unsigned short*)(ws + 5767168);    // 16MB each, [8][4096][256]
  unsigned short* QlB = (unsigned short*)(ws + 22544384);
  unsigned short* KhB = (unsigned short*)(ws + 39321600);
  unsigned short* KlB = (unsigned short*)(ws + 56098816);
  unsigned short* VhT = (unsigned short*)(ws + 72876032);   // 16MB each, [8][256][4096]
  unsigned short* VlT = (unsigned short*)(ws + 89653248);
  // total ws usage: ~101.5 MB

  k_fc1<<<8192, 256, 0, stream>>>(x, fc1_w, fc1_b, h_t);
  k_conv1<<<dim3(512, 2), 256, 0, stream>>>(
      h_t, c1q_w, c1q_b, c1v_w, c1v_b,
      bn1q_g, bn1q_be, bn1q_m, bn1q_v,
      bn1k_g, bn1k_be, bn1k_m, bn1k_v,
      bn1v_g, bn1v_be, bn1v_m, bn1v_v,
      T1q, T1k, T1v);
  k_conv2<<<dim3(8, 3, 2), 256, 0, stream>>>(
      T1q, T1k, T1v, c2q_w, c2q_b, c2v_w, c2v_b,
      bn2q_g, bn2q_be, bn2q_m, bn2q_v,
      bn2k_g, bn2k_be, bn2k_m, bn2k_v,
      bn2v_g, bn2v_be, bn2v_m, bn2v_v,
      Q2H, Q2L, K2H, K2L, V2H, V2L);
  k_conv3qk<<<dim3(64, 8), 256, 0, stream>>>(
      c3q_w, c3q_b, Q2H, Q2L, QhB, QlB, 0.08838834764831845f);
  k_conv3qk<<<dim3(64, 8), 256, 0, stream>>>(
      c3k_w, c3k_b, K2H, K2L, KhB, KlB, 1.0f);
  k_conv3v<<<dim3(16, 4, 8), 256, 0, stream>>>(c3v_w, c3v_b, V2H, V2L, VhT, VlT);
  k_attn<<<512, 256, 0, stream>>>(QhB, QlB, KhB, KlB, VhT, VlT, co_w, co_b,
                                  (float*)d_out);
}

// Round 5
// 1134.634 us; speedup vs baseline: 1.2776x; 1.2776x over previous
//
#include <hip/hip_runtime.h>
#include <cstdint>
#include <cstddef>

#define EPS 1e-5f

typedef __attribute__((ext_vector_type(8))) short bf16x8;
typedef __attribute__((ext_vector_type(4))) float f32x4;
typedef __attribute__((ext_vector_type(16))) float f32x16;

__device__ __forceinline__ unsigned short rne_bf16(float f) {
  union { float f; unsigned int u; } v; v.f = f;
  unsigned int u = v.u;
  return (unsigned short)((u + 0x7fffu + ((u >> 16) & 1u)) >> 16);
}
__device__ __forceinline__ float bf16_to_f(unsigned short h) {
  union { unsigned int u; float f; } v; v.u = ((unsigned int)h) << 16; return v.f;
}
// split fp32 into hi/lo bf16 pair: hi+lo represents v to ~2^-17 relative
__device__ __forceinline__ void split_hl(float v, unsigned short& h, unsigned short& l) {
  h = rne_bf16(v);
  l = rne_bf16(v - bf16_to_f(h));
}
__device__ __forceinline__ f32x4 mfma16(bf16x8 a, bf16x8 b, f32x4 c) {
  return __builtin_amdgcn_mfma_f32_16x16x32_bf16(a, b, c, 0, 0, 0);
}
__device__ __forceinline__ f32x16 mfma32(bf16x8 a, bf16x8 b, f32x16 c) {
  return __builtin_amdgcn_mfma_f32_32x32x16_bf16(a, b, c, 0, 0, 0);
}

// ---------------------------------------------------------------------------
// Stage 1: fc1. h_t[b][k][m] = x[b]·fc1_w[m*128+k] + fc1_b.  One wave per row.
// ---------------------------------------------------------------------------
__global__ __launch_bounds__(256) void k_fc1(const float* __restrict__ x,
                                             const float* __restrict__ w,
                                             const float* __restrict__ bias,
                                             float* __restrict__ h_t) {
  const int lane = threadIdx.x & 63;
  const int wv = threadIdx.x >> 6;
  const int r = blockIdx.x * 4 + wv;               // weight row 0..32767
  const float4* wr = (const float4*)(w + (size_t)r * 1024);
  float acc[8] = {0, 0, 0, 0, 0, 0, 0, 0};
#pragma unroll
  for (int i = 0; i < 4; ++i) {
    float4 wv4 = wr[lane + i * 64];
#pragma unroll
    for (int b = 0; b < 8; ++b) {
      float4 xv = ((const float4*)(x + b * 1024))[lane + i * 64];
      acc[b] += wv4.x * xv.x + wv4.y * xv.y + wv4.z * xv.z + wv4.w * xv.w;
    }
  }
#pragma unroll
  for (int d = 1; d < 64; d <<= 1) {
#pragma unroll
    for (int b = 0; b < 8; ++b) acc[b] += __shfl_xor(acc[b], d);
  }
  if (lane == 0) {
    const int mm = r >> 7, kk = r & 127;
    const float bb = bias[r];
#pragma unroll
    for (int b = 0; b < 8; ++b) h_t[b * 32768 + kk * 256 + mm] = acc[b] + bb;
  }
}

// ---------------------------------------------------------------------------
// Stage 2a: conv1 + BN + ReLU (fp32).
// ---------------------------------------------------------------------------
__global__ __launch_bounds__(256) void k_conv1(
    const float* __restrict__ h_t,
    const float* __restrict__ c1q_w, const float* __restrict__ c1q_b,
    const float* __restrict__ c1v_w, const float* __restrict__ c1v_b,
    const float* __restrict__ g1q, const float* __restrict__ be1q,
    const float* __restrict__ mu1q, const float* __restrict__ va1q,
    const float* __restrict__ g1k, const float* __restrict__ be1k,
    const float* __restrict__ mu1k, const float* __restrict__ va1k,
    const float* __restrict__ g1v, const float* __restrict__ be1v,
    const float* __restrict__ mu1v, const float* __restrict__ va1v,
    float* __restrict__ T1q, float* __restrict__ T1k, float* __restrict__ T1v) {
  const int m = threadIdx.x;
  const int o = blockIdx.x & 63;
  const int b = blockIdx.x >> 6;
  const int path = blockIdx.y;
  const float* w = (path == 0 ? c1q_w : c1v_w) + o * 128;
  const float* h = h_t + b * 32768 + m;
  float acc = 0.f;
#pragma unroll 8
  for (int c = 0; c < 128; ++c) acc += w[c] * h[c * 256];
  if (path == 0) {
    const float z = acc + c1q_b[o];
    const float sq = g1q[o] / sqrtf(va1q[o] + EPS);
    T1q[b * 16384 + o * 256 + m] = fmaxf((z - mu1q[o]) * sq + be1q[o], 0.f);
    const float sk = g1k[o] / sqrtf(va1k[o] + EPS);
    T1k[b * 16384 + o * 256 + m] = fmaxf((z - mu1k[o]) * sk + be1k[o], 0.f);
  } else {
    const float z = acc + c1v_b[o];
    const float sv = g1v[o] / sqrtf(va1v[o] + EPS);
    T1v[b * 16384 + o * 256 + m] = fmaxf((z - mu1v[o]) * sv + be1v[o], 0.f);
  }
}

// ---------------------------------------------------------------------------
// Stage 2b: conv2 + BN + ReLU, output TRANSPOSED hi/lo bf16 [b][m(256)][c2(128)]
// ---------------------------------------------------------------------------
__global__ __launch_bounds__(256) void k_conv2(
    const float* __restrict__ T1q, const float* __restrict__ T1k,
    const float* __restrict__ T1v,
    const float* __restrict__ c2q_w, const float* __restrict__ c2q_b,
    const float* __restrict__ c2v_w, const float* __restrict__ c2v_b,
    const float* __restrict__ g2q, const float* __restrict__ be2q,
    const float* __restrict__ mu2q, const float* __restrict__ va2q,
    const float* __restrict__ g2k, const float* __restrict__ be2k,
    const float* __restrict__ mu2k, const float* __restrict__ va2k,
    const float* __restrict__ g2v, const float* __restrict__ be2v,
    const float* __restrict__ mu2v, const float* __restrict__ va2v,
    unsigned short* __restrict__ Q2H, unsigned short* __restrict__ Q2L,
    unsigned short* __restrict__ K2H, unsigned short* __restrict__ K2L,
    unsigned short* __restrict__ V2H, unsigned short* __restrict__ V2L) {
  const int m = threadIdx.x;
  const int b = blockIdx.x;
  const int path = blockIdx.y;
  const int oc = blockIdx.z;
  const float* T1 = (path == 0 ? T1q : path == 1 ? T1k : T1v) + b * 16384 + m;
  const float* w = (path == 2 ? c2v_w : c2q_w);
  const float* cb = (path == 2 ? c2v_b : c2q_b);
  const float* g = (path == 0 ? g2q : path == 1 ? g2k : g2v);
  const float* be = (path == 0 ? be2q : path == 1 ? be2k : be2v);
  const float* mu = (path == 0 ? mu2q : path == 1 ? mu2k : mu2v);
  const float* va = (path == 0 ? va2q : path == 1 ? va2k : va2v);
  float t[64];
#pragma unroll 8
  for (int c = 0; c < 64; ++c) t[c] = T1[c * 256];
  unsigned short* oh =
      (path == 0 ? Q2H : path == 1 ? K2H : V2H) + b * 32768 + m * 128 + oc * 64;
  unsigned short* ol =
      (path == 0 ? Q2L : path == 1 ? K2L : V2L) + b * 32768 + m * 128 + oc * 64;
  for (int og = 0; og < 8; ++og) {
    bf16x8 ph, pl;
#pragma unroll
    for (int j = 0; j < 8; ++j) {
      const int o = oc * 64 + og * 8 + j;
      float acc = cb[o];
      const float* wo = w + o * 64;
#pragma unroll 8
      for (int c = 0; c < 64; ++c) acc += wo[c] * t[c];
      const float s = g[o] / sqrtf(va[o] + EPS);
      const float val = fmaxf((acc - mu[o]) * s + be[o], 0.f);
      unsigned short hh, ll;
      split_hl(val, hh, ll);
      ph[j] = (short)hh; pl[j] = (short)ll;
    }
    *(bf16x8*)(oh + og * 8) = ph;
    *(bf16x8*)(ol + og * 8) = pl;
  }
}

// ---------------------------------------------------------------------------
// Stage 3a: conv3 for Q or K via split-MFMA (~fp32), output hi/lo bf16 pair
// Y[b][n][m].  Q scaled by 1/sqrt(128).
// ---------------------------------------------------------------------------
__global__ __launch_bounds__(256) void k_conv3qk(
    const float* __restrict__ W, const float* __restrict__ bias,
    const unsigned short* __restrict__ Xh, const unsigned short* __restrict__ Xl,
    unsigned short* __restrict__ Yh, unsigned short* __restrict__ Yl,
    float scale) {
  const int lane = threadIdx.x & 63, wv = threadIdx.x >> 6;
  const int l15 = lane & 15, quad = lane >> 4;
  const int b = blockIdx.y;
  const unsigned short* XH = Xh + b * 32768;
  const unsigned short* XL = Xl + b * 32768;
  unsigned short* YH = Yh + (size_t)b * 4096 * 256;
  unsigned short* YL = Yl + (size_t)b * 4096 * 256;
  const int nb = blockIdx.x * 64 + wv * 16;
  const float* wr = W + (size_t)(nb + l15) * 128 + quad * 8;
  bf16x8 ah[4], al[4];
#pragma unroll
  for (int ks = 0; ks < 4; ++ks) {
#pragma unroll
    for (int j = 0; j < 8; ++j) {
      unsigned short hh, ll;
      split_hl(wr[ks * 32 + j], hh, ll);
      ah[ks][j] = (short)hh; al[ks][j] = (short)ll;
    }
  }
  f32x4 acc[16];
#pragma unroll
  for (int ms = 0; ms < 16; ++ms) acc[ms] = (f32x4){0, 0, 0, 0};
#pragma unroll
  for (int ks = 0; ks < 4; ++ks) {
#pragma unroll
    for (int ms = 0; ms < 16; ++ms) {
      const size_t off = (size_t)(ms * 16 + l15) * 128 + ks * 32 + quad * 8;
      bf16x8 bh = *(const bf16x8*)(XH + off);
      bf16x8 bl = *(const bf16x8*)(XL + off);
      acc[ms] = mfma16(ah[ks], bh, acc[ms]);
      acc[ms] = mfma16(al[ks], bh, acc[ms]);
      acc[ms] = mfma16(ah[ks], bl, acc[ms]);
    }
  }
#pragma unroll
  for (int r = 0; r < 4; ++r) {
    const int n = nb + quad * 4 + r;
    const float bv = bias[n];
#pragma unroll
    for (int ms = 0; ms < 16; ++ms) {
      const float v = (acc[ms][r] + bv) * scale;
      unsigned short hh, ll;
      split_hl(v, hh, ll);
      YH[(size_t)n * 256 + ms * 16 + l15] = hh;
      YL[(size_t)n * 256 + ms * 16 + l15] = ll;
    }
  }
}

// ---------------------------------------------------------------------------
// Stage 3b: conv3 for V (split-MFMA), output PRE-TRANSPOSED hi/lo bf16
// VhT/VlT [b][m(256)][n(4096)].
// ---------------------------------------------------------------------------
__global__ __launch_bounds__(256) void k_conv3v(
    const float* __restrict__ c3v_w, const float* __restrict__ c3v_b,
    const unsigned short* __restrict__ V2H, const unsigned short* __restrict__ V2L,
    unsigned short* __restrict__ VhT, unsigned short* __restrict__ VlT) {
  const int lane = threadIdx.x & 63, wv = threadIdx.x >> 6;
  const int l15 = lane & 15, quad = lane >> 4;
  const int b = blockIdx.z;
  const int nb0 = blockIdx.x * 256;
  const int mb = blockIdx.y * 64 + wv * 16;
  const size_t xoff = b * 32768 + (size_t)(mb + l15) * 128 + quad * 8;
  bf16x8 ah[4], al[4];
#pragma unroll
  for (int ks = 0; ks < 4; ++ks) {
    ah[ks] = *(const bf16x8*)(V2H + xoff + ks * 32);
    al[ks] = *(const bf16x8*)(V2L + xoff + ks * 32);
  }
  f32x4 acc[16];
#pragma unroll
  for (int ns = 0; ns < 16; ++ns) acc[ns] = (f32x4){0, 0, 0, 0};
#pragma unroll
  for (int ks = 0; ks < 4; ++ks) {
#pragma unroll
    for (int ns = 0; ns < 16; ++ns) {
      const float* wr = c3v_w + (size_t)(nb0 + ns * 16 + l15) * 128 + ks * 32 + quad * 8;
      bf16x8 bh, bl;
#pragma unroll
      for (int j = 0; j < 8; ++j) {
        unsigned short hh, ll;
        split_hl(wr[j], hh, ll);
        bh[j] = (short)hh; bl[j] = (short)ll;
      }
      acc[ns] = mfma16(ah[ks], bh, acc[ns]);
      acc[ns] = mfma16(al[ks], bh, acc[ns]);
      acc[ns] = mfma16(ah[ks], bl, acc[ns]);
    }
  }
#pragma unroll
  for (int ns = 0; ns < 16; ++ns) {
    const int n = nb0 + ns * 16 + l15;
    const float bv = c3v_b[n];
#pragma unroll
    for (int r = 0; r < 4; ++r) {
      const int m = mb + quad * 4 + r;
      unsigned short hh, ll;
      split_hl(acc[ns][r] + bv, hh, ll);
      VhT[(size_t)b * 1048576 + (size_t)m * 4096 + n] = hh;
      VlT[(size_t)b * 1048576 + (size_t)m * 4096 + n] = ll;
    }
  }
}

// ---------------------------------------------------------------------------
// Stage 4: flash attention on 32x32x16 MFMA (2x FLOP per LDS fragment byte,
// 32 q-rows/wave => 2x K/V fragment reuse; ~2.9x less LDS read traffic).
// Numerics identical to R4: S = QhKh+QlKh+QhKl; P=exp(S) hi/lo;
// O += PhVh+PlVh+PhVl; l = sum(Ph+Pl).  Block = 4 waves = 128 q-rows.
// Layouts: C/D row=(reg&3)+8*(reg>>2)+4*(lane>>5), col=lane&31 (verified);
// A/B: dim=lane&31, k=(lane>>5)*8+i (generalization of verified 16x16x32).
// ---------------------------------------------------------------------------
__global__ __launch_bounds__(256, 1) void k_attn(
    const unsigned short* __restrict__ Qh, const unsigned short* __restrict__ Ql,
    const unsigned short* __restrict__ Kh, const unsigned short* __restrict__ Kl,
    const unsigned short* __restrict__ VhT, const unsigned short* __restrict__ VlT,
    const float* __restrict__ co_w, const float* __restrict__ co_b,
    float* __restrict__ out) {
  __shared__ __align__(16) short Kth[32 * 264];   // K hi tile [32][256] pad 264
  __shared__ __align__(16) short Ktl[32 * 264];   // K lo tile
  __shared__ __align__(16) short VTh[256 * 40];   // V^T hi [m=256][j=32] pad 40
  __shared__ __align__(16) short VTl[256 * 40];   // V^T lo
  __shared__ __align__(16) short Pb[4 * 32 * 72]; // per-wave P [32 q][Ph 0-31|Pl 32-63] pad 72
  __shared__ float cw[768];
  const int t = threadIdx.x;
  const int lane = t & 63, wv = t >> 6;
  const int l31 = lane & 31, half = lane >> 5;
  const int b = blockIdx.x & 7;     // batch ~pinned per-XCD for K/V L2 locality
  const int qt = blockIdx.x >> 3;
  for (int i = t; i < 768; i += 256) cw[i] = co_w[i];
  // Q fragments for this wave's 32 q-rows (A-operand layout), hi+lo resident
  const int qrow = qt * 128 + wv * 32 + l31;
  const size_t qoff = ((size_t)b * 4096 + qrow) * 256 + half * 8;
  bf16x8 qfh[16], qfl[16];
#pragma unroll
  for (int kc = 0; kc < 16; ++kc) {
    qfh[kc] = *(const bf16x8*)(Qh + qoff + kc * 16);
    qfl[kc] = *(const bf16x8*)(Ql + qoff + kc * 16);
  }
  f32x16 O[8];
#pragma unroll
  for (int mt = 0; mt < 8; ++mt)
#pragma unroll
    for (int r = 0; r < 16; ++r) O[mt][r] = 0.f;
  float lp[16];
#pragma unroll
  for (int r = 0; r < 16; ++r) lp[r] = 0.f;
  const unsigned short* Kgh = Kh + (size_t)b * 4096 * 256;
  const unsigned short* Kgl = Kl + (size_t)b * 4096 * 256;
  const unsigned short* Vgh = VhT + (size_t)b * 1048576;
  const unsigned short* Vgl = VlT + (size_t)b * 1048576;
  short* Pw = Pb + wv * (32 * 72);

  for (int jt = 0; jt < 128; ++jt) {
    const int jbase = jt * 32;
#pragma unroll
    for (int i = 0; i < 4; ++i) {  // stage K hi/lo [32 rows][256]
      const int c = i * 256 + t;
      const int row = c >> 5, seg = (c & 31) * 8;
      const size_t g = (size_t)(jbase + row) * 256 + seg;
      *(bf16x8*)&Kth[row * 264 + seg] = *(const bf16x8*)(Kgh + g);
      *(bf16x8*)&Ktl[row * 264 + seg] = *(const bf16x8*)(Kgl + g);
    }
#pragma unroll
    for (int i = 0; i < 4; ++i) {  // stage V^T hi/lo [256 m][32 j]
      const int c = i * 256 + t;
      const int mr = c >> 2, seg = (c & 3) * 8;
      const size_t g = (size_t)mr * 4096 + jbase + seg;
      *(bf16x8*)&VTh[mr * 40 + seg] = *(const bf16x8*)(Vgh + g);
      *(bf16x8*)&VTl[mr * 40 + seg] = *(const bf16x8*)(Vgl + g);
    }
    __syncthreads();
    // S[32q][32j] = QK^T via 3 split chains (scale pre-folded into Q)
    f32x16 s;
#pragma unroll
    for (int r = 0; r < 16; ++r) s[r] = 0.f;
#pragma unroll
    for (int kc = 0; kc < 16; ++kc) {
      bf16x8 kh = *(const bf16x8*)&Kth[l31 * 264 + kc * 16 + half * 8];
      bf16x8 kl = *(const bf16x8*)&Ktl[l31 * 264 + kc * 16 + half * 8];
      s = mfma32(qfh[kc], kh, s);
      s = mfma32(qfl[kc], kh, s);
      s = mfma32(qfh[kc], kl, s);
    }
    // P = exp(S) hi/lo -> LDS (C/D layout -> A layout round-trip)
#pragma unroll
    for (int r = 0; r < 16; ++r) {
      const float p = expf(s[r]);
      unsigned short ph, pl;
      split_hl(p, ph, pl);
      lp[r] += bf16_to_f(ph) + bf16_to_f(pl);  // l == weights actually used
      const int q = (r & 3) + 8 * (r >> 2) + 4 * half;
      Pw[q * 72 + l31] = (short)ph;
      Pw[q * 72 + 32 + l31] = (short)pl;
    }
    __syncthreads();  // P visible (barrier drains LDS writes)
    bf16x8 pfh[2], pfl[2];
#pragma unroll
    for (int jc = 0; jc < 2; ++jc) {
      pfh[jc] = *(const bf16x8*)&Pw[l31 * 72 + jc * 16 + half * 8];
      pfl[jc] = *(const bf16x8*)&Pw[l31 * 72 + 32 + jc * 16 + half * 8];
    }
#pragma unroll
    for (int mt = 0; mt < 8; ++mt) {  // O += PhVh + PlVh + PhVl
#pragma unroll
      for (int jc = 0; jc < 2; ++jc) {
        bf16x8 vh = *(const bf16x8*)&VTh[(mt * 32 + l31) * 40 + jc * 16 + half * 8];
        bf16x8 vl = *(const bf16x8*)&VTl[(mt * 32 + l31) * 40 + jc * 16 + half * 8];
        O[mt] = mfma32(pfh[jc], vh, O[mt]);
        O[mt] = mfma32(pfl[jc], vh, O[mt]);
        O[mt] = mfma32(pfh[jc], vl, O[mt]);
      }
    }
    __syncthreads();  // protect tiles before next staging
  }
  // reduce l over the 32 j-lanes of each half-wave (halves own disjoint q-sets)
#pragma unroll
  for (int r = 0; r < 16; ++r) {
#pragma unroll
    for (int d = 1; d < 32; d <<= 1) lp[r] += __shfl_xor(lp[r], d);
  }
  // fused epilogue: out[b][row][o] = co_w[o]·O_row / l + co_b[o]
  float part[16][3];
#pragma unroll
  for (int r = 0; r < 16; ++r)
#pragma unroll
    for (int o = 0; o < 3; ++o) part[r][o] = 0.f;
#pragma unroll
  for (int mt = 0; mt < 8; ++mt) {
    const int m = mt * 32 + l31;
    const float c0 = cw[m], c1 = cw[256 + m], c2 = cw[512 + m];
#pragma unroll
    for (int r = 0; r < 16; ++r) {
      const float ov = O[mt][r];
      part[r][0] += ov * c0;
      part[r][1] += ov * c1;
      part[r][2] += ov * c2;
    }
  }
#pragma unroll
  for (int r = 0; r < 16; ++r) {
#pragma unroll
    for (int o = 0; o < 3; ++o) {
      float v = part[r][o];
#pragma unroll
      for (int d = 1; d < 32; d <<= 1) v += __shfl_xor(v, d);
      part[r][o] = v;
    }
  }
  if (l31 < 16) {
    const int r = l31;
    const int q = (r & 3) + 8 * (r >> 2) + 4 * half;
    const int row_g = qt * 128 + wv * 32 + q;
    const float rl = 1.f / lp[r];
#pragma unroll
    for (int o = 0; o < 3; ++o)
      out[(size_t)b * 12288 + (size_t)row_g * 3 + o] = part[r][o] * rl + co_b[o];
  }
}

// ---------------------------------------------------------------------------
extern "C" void kernel_launch(void* const* d_in, const int* in_sizes, int n_in,
                              void* d_out, int out_size, void* d_ws, size_t ws_size,
                              hipStream_t stream) {
  const float* x = (const float*)d_in[0];
  const float* fc1_w = (const float*)d_in[1];
  const float* fc1_b = (const float*)d_in[2];
  const float* c1q_w = (const float*)d_in[3];
  const float* c1q_b = (const float*)d_in[4];
  const float* c2q_w = (const float*)d_in[5];
  const float* c2q_b = (const float*)d_in[6];
  const float* c3q_w = (const float*)d_in[7];
  const float* c3q_b = (const float*)d_in[8];
  const float* c3k_w = (const float*)d_in[9];
  const float* c3k_b = (const float*)d_in[10];
  const float* c1v_w = (const float*)d_in[11];
  const float* c1v_b = (const float*)d_in[12];
  const float* c2v_w = (const float*)d_in[13];
  const float* c2v_b = (const float*)d_in[14];
  const float* c3v_w = (const float*)d_in[15];
  const float* c3v_b = (const float*)d_in[16];
  const float* bn1q_g = (const float*)d_in[17];
  const float* bn1q_be = (const float*)d_in[18];
  const float* bn1q_m = (const float*)d_in[19];
  const float* bn1q_v = (const float*)d_in[20];
  const float* bn2q_g = (const float*)d_in[21];
  const float* bn2q_be = (const float*)d_in[22];
  const float* bn2q_m = (const float*)d_in[23];
  const float* bn2q_v = (const float*)d_in[24];
  const float* bn1k_g = (const float*)d_in[25];
  const float* bn1k_be = (const float*)d_in[26];
  const float* bn1k_m = (const float*)d_in[27];
  const float* bn1k_v = (const float*)d_in[28];
  const float* bn2k_g = (const float*)d_in[29];
  const float* bn2k_be = (const float*)d_in[30];
  const float* bn2k_m = (const float*)d_in[31];
  const float* bn2k_v = (const float*)d_in[32];
  const float* bn1v_g = (const float*)d_in[33];
  const float* bn1v_be = (const float*)d_in[34];
  const float* bn1v_m = (const float*)d_in[35];
  const float* bn1v_v = (const float*)d_in[36];
  const float* bn2v_g = (const float*)d_in[37];
  const float* bn2v_be = (const float*)d_in[38];
  const float* bn2v_m = (const float*)d_in[39];
  const float* bn2v_v = (const float*)d_in[40];
  const float* co_w = (const float*)d_in[41];
  const float* co_b = (const float*)d_in[42];

  char* ws = (char*)d_ws;
  float* h_t = (float*)(ws + 0);                            // 1 MB [8][128][256]
  float* T1q = (float*)(ws + 1048576);                      // 512KB each
  float* T1k = (float*)(ws + 1572864);
  float* T1v = (float*)(ws + 2097152);
  unsigned short* Q2H = (unsigned short*)(ws + 2621440);    // 512KB each, [8][256][128]
  unsigned short* Q2L = (unsigned short*)(ws + 3145728);
  unsigned short* K2H = (unsigned short*)(ws + 3670016);
  unsigned short* K2L = (unsigned short*)(ws + 4194304);
  unsigned short* V2H = (unsigned short*)(ws + 4718592);
  unsigned short* V2L = (unsigned short*)(ws + 5242880);
  unsigned short* QhB = (unsigned short*)(ws + 5767168);    // 16MB each, [8][4096][256]
  unsigned short* QlB = (unsigned short*)(ws + 22544384);
  unsigned short* KhB = (unsigned short*)(ws + 39321600);
  unsigned short* KlB = (unsigned short*)(ws + 56098816);
  unsigned short* VhT = (unsigned short*)(ws + 72876032);   // 16MB each, [8][256][4096]
  unsigned short* VlT = (unsigned short*)(ws + 89653248);
  // total ws usage: ~101.5 MB

  k_fc1<<<8192, 256, 0, stream>>>(x, fc1_w, fc1_b, h_t);
  k_conv1<<<dim3(512, 2), 256, 0, stream>>>(
      h_t, c1q_w, c1q_b, c1v_w, c1v_b,
      bn1q_g, bn1q_be, bn1q_m, bn1q_v,
      bn1k_g, bn1k_be, bn1k_m, bn1k_v,
      bn1v_g, bn1v_be, bn1v_m, bn1v_v,
      T1q, T1k, T1v);
  k_conv2<<<dim3(8, 3, 2), 256, 0, stream>>>(
      T1q, T1k, T1v, c2q_w, c2q_b, c2v_w, c2v_b,
      bn2q_g, bn2q_be, bn2q_m, bn2q_v,
      bn2k_g, bn2k_be, bn2k_m, bn2k_v,
      bn2v_g, bn2v_be, bn2v_m, bn2v_v,
      Q2H, Q2L, K2H, K2L, V2H, V2L);
  k_conv3qk<<<dim3(64, 8), 256, 0, stream>>>(
      c3q_w, c3q_b, Q2H, Q2L, QhB, QlB, 0.08838834764831845f);
  k_conv3qk<<<dim3(64, 8), 256, 0, stream>>>(
      c3k_w, c3k_b, K2H, K2L, KhB, KlB, 1.0f);
  k_conv3v<<<dim3(16, 4, 8), 256, 0, stream>>>(c3v_w, c3v_b, V2H, V2L, VhT, VlT);
  k_attn<<<256, 256, 0, stream>>>(QhB, QlB, KhB, KlB, VhT, VlT, co_w, co_b,
                                  (float*)d_out);
}